// Round 1
// baseline (27.966 us; speedup 1.0000x reference)
//
#include <hip/hip_runtime.h>

// Problem constants: B=4096, N=16, E=512, T=128, S=256
// Outputs: aggregated_repr (B,E) then attention_weights (B,N), both f32, concat flat.
//
// Note: the task_anchor @ v_t term is a per-b constant added to all N scores;
// softmax is shift-invariant, so task_anchor and scene_repr are dead inputs.

#define NB 4096
#define NEXP 16
#define EDIM 512

__global__ __launch_bounds__(256, 2) void meta_attn_kernel(
    const float* __restrict__ expert,   // [B, 16, 512]
    const float* __restrict__ v,        // [640, 1]; v_e = v[0:512]
    float* __restrict__ out_agg,        // [B, 512]
    float* __restrict__ out_w)          // [B, 16]
{
    const int wave = threadIdx.x >> 6;
    const int lane = threadIdx.x & 63;
    const int b = blockIdx.x * 4 + wave;

    const float* row = expert + (size_t)b * (NEXP * EDIM);

    // Each lane owns e-chunks [4*lane, 4*lane+4) and [256+4*lane, 256+4*lane+4)
    const float4 ve0 = *(const float4*)(v + 4 * lane);
    const float4 ve1 = *(const float4*)(v + 256 + 4 * lane);

    float4 tile[NEXP][2];   // register-resident: 128 VGPRs
    float s[NEXP];

    // Pass 1: load tile + per-lane partial dot with v_e
#pragma unroll
    for (int n = 0; n < NEXP; ++n) {
        tile[n][0] = *(const float4*)(row + n * EDIM + 4 * lane);
        tile[n][1] = *(const float4*)(row + n * EDIM + 256 + 4 * lane);
        const float4 a = tile[n][0];
        const float4 c = tile[n][1];
        s[n] = a.x * ve0.x + a.y * ve0.y + a.z * ve0.z + a.w * ve0.w
             + c.x * ve1.x + c.y * ve1.y + c.z * ve1.z + c.w * ve1.w;
    }

    // Butterfly-reduce each score across the 64-lane wave (all lanes get total)
#pragma unroll
    for (int n = 0; n < NEXP; ++n) {
        float x = s[n];
#pragma unroll
        for (int m = 1; m < 64; m <<= 1)
            x += __shfl_xor(x, m, 64);
        s[n] = x;
    }

    // Softmax over the 16 scores (computed redundantly in every lane)
    float mx = s[0];
#pragma unroll
    for (int n = 1; n < NEXP; ++n) mx = fmaxf(mx, s[n]);
    float w[NEXP];
    float sum = 0.0f;
#pragma unroll
    for (int n = 0; n < NEXP; ++n) {
        w[n] = __expf(s[n] - mx);
        sum += w[n];
    }
    const float inv = 1.0f / sum;
#pragma unroll
    for (int n = 0; n < NEXP; ++n) w[n] *= inv;

    // Pass 2: weighted sum over n from the register tile (no global re-read)
    float4 acc0 = make_float4(0.f, 0.f, 0.f, 0.f);
    float4 acc1 = make_float4(0.f, 0.f, 0.f, 0.f);
#pragma unroll
    for (int n = 0; n < NEXP; ++n) {
        const float wn = w[n];
        acc0.x += wn * tile[n][0].x;
        acc0.y += wn * tile[n][0].y;
        acc0.z += wn * tile[n][0].z;
        acc0.w += wn * tile[n][0].w;
        acc1.x += wn * tile[n][1].x;
        acc1.y += wn * tile[n][1].y;
        acc1.z += wn * tile[n][1].z;
        acc1.w += wn * tile[n][1].w;
    }

    *(float4*)(out_agg + (size_t)b * EDIM + 4 * lane)       = acc0;
    *(float4*)(out_agg + (size_t)b * EDIM + 256 + 4 * lane) = acc1;

    // Weights: 16 predicated scalar stores (compile-time index into w[])
#pragma unroll
    for (int n = 0; n < NEXP; ++n)
        if (lane == n) out_w[(size_t)b * NEXP + n] = w[n];
}

extern "C" void kernel_launch(void* const* d_in, const int* in_sizes, int n_in,
                              void* d_out, int out_size, void* d_ws, size_t ws_size,
                              hipStream_t stream) {
    // d_in: 0=scene_repr (unused), 1=task_anchor (unused), 2=expert_reprs, 3=v
    const float* expert = (const float*)d_in[2];
    const float* v      = (const float*)d_in[3];
    float* out_agg = (float*)d_out;
    float* out_w   = (float*)d_out + (size_t)NB * EDIM;

    meta_attn_kernel<<<dim3(NB / 4), dim3(256), 0, stream>>>(expert, v, out_agg, out_w);
}

// Round 2
// 27.597 us; speedup vs baseline: 1.0134x; 1.0134x over previous
//
#include <hip/hip_runtime.h>

// Problem: B=4096, N=16, E=512, T=128, S=256
// Outputs: aggregated_repr (B,E) then attention_weights (B,N), both f32, concat flat.
//
// task_anchor @ v_t is a per-b constant added to all N scores; softmax is
// shift-invariant, so task_anchor and scene_repr are dead inputs.
// Traffic floor: 134.2 MB read + 8.65 MB write ≈ 143 MB.

#define NB 4096
#define NEXP 16
#define EDIM 512

typedef float f32x4 __attribute__((ext_vector_type(4)));

__global__ __launch_bounds__(256, 2) void meta_attn_kernel(
    const float* __restrict__ expert,   // [B, 16, 512]
    const float* __restrict__ v,        // [640, 1]; v_e = v[0:512]
    float* __restrict__ out_agg,        // [B, 512]
    float* __restrict__ out_w)          // [B, 16]
{
    const int wave = threadIdx.x >> 6;
    const int lane = threadIdx.x & 63;
    const int b = blockIdx.x * 4 + wave;

    const float* row = expert + (size_t)b * (NEXP * EDIM);

    // v is reused by every block: keep it cached (regular loads)
    const f32x4 ve0 = *(const f32x4*)(v + 4 * lane);
    const f32x4 ve1 = *(const f32x4*)(v + 256 + 4 * lane);

    f32x4 tile[NEXP][2];   // register-resident: 128 VGPRs

    // Phase 1: issue ALL 32 nontemporal loads before any dependent use
    // (each load instruction covers a contiguous 1 KB wave segment)
#pragma unroll
    for (int n = 0; n < NEXP; ++n) {
        tile[n][0] = __builtin_nontemporal_load(
            (const f32x4*)(row + n * EDIM + 4 * lane));
        tile[n][1] = __builtin_nontemporal_load(
            (const f32x4*)(row + n * EDIM + 256 + 4 * lane));
    }

    // Phase 2: per-lane partial dots
    float s[NEXP];
#pragma unroll
    for (int n = 0; n < NEXP; ++n) {
        const f32x4 a = tile[n][0];
        const f32x4 c = tile[n][1];
        s[n] = a.x * ve0.x + a.y * ve0.y + a.z * ve0.z + a.w * ve0.w
             + c.x * ve1.x + c.y * ve1.y + c.z * ve1.z + c.w * ve1.w;
    }

    // Butterfly-reduce each score across the 64-lane wave (16 independent
    // chains — compiler interleaves them, DS latency pipelined)
#pragma unroll
    for (int n = 0; n < NEXP; ++n) {
        float x = s[n];
#pragma unroll
        for (int m = 1; m < 64; m <<= 1)
            x += __shfl_xor(x, m, 64);
        s[n] = x;
    }

    // Softmax over 16 scores (redundant in every lane — no divergence)
    float mx = s[0];
#pragma unroll
    for (int n = 1; n < NEXP; ++n) mx = fmaxf(mx, s[n]);
    float w[NEXP];
    float sum = 0.0f;
#pragma unroll
    for (int n = 0; n < NEXP; ++n) {
        w[n] = __expf(s[n] - mx);
        sum += w[n];
    }
    const float inv = 1.0f / sum;
#pragma unroll
    for (int n = 0; n < NEXP; ++n) w[n] *= inv;

    // Phase 3: weighted sum from the register tile (no global re-read)
    f32x4 acc0 = {0.f, 0.f, 0.f, 0.f};
    f32x4 acc1 = {0.f, 0.f, 0.f, 0.f};
#pragma unroll
    for (int n = 0; n < NEXP; ++n) {
        const float wn = w[n];
        acc0 += wn * tile[n][0];
        acc1 += wn * tile[n][1];
    }

    __builtin_nontemporal_store(acc0, (f32x4*)(out_agg + (size_t)b * EDIM + 4 * lane));
    __builtin_nontemporal_store(acc1, (f32x4*)(out_agg + (size_t)b * EDIM + 256 + 4 * lane));

    // Weights: 16 predicated scalar stores (compile-time index into w[])
#pragma unroll
    for (int n = 0; n < NEXP; ++n)
        if (lane == n) out_w[(size_t)b * NEXP + n] = w[n];
}

extern "C" void kernel_launch(void* const* d_in, const int* in_sizes, int n_in,
                              void* d_out, int out_size, void* d_ws, size_t ws_size,
                              hipStream_t stream) {
    // d_in: 0=scene_repr (unused), 1=task_anchor (unused), 2=expert_reprs, 3=v
    const float* expert = (const float*)d_in[2];
    const float* v      = (const float*)d_in[3];
    float* out_agg = (float*)d_out;
    float* out_w   = (float*)d_out + (size_t)NB * EDIM;

    meta_attn_kernel<<<dim3(NB / 4), dim3(256), 0, stream>>>(expert, v, out_agg, out_w);
}